// Round 5
// baseline (5634.731 us; speedup 1.0000x reference)
//
#include <hip/hip_runtime.h>
#include <hip/hip_bf16.h>

// SimpleSAGE on MI355X — bf16 features, MFMA GEMMs, fused bucket-SpMM.
//   xw  = x @ w1                      [N,128] bf16  (mfma gemm, K=256)
//   h1  = relu(spmm(xw) + b1)         [N,128] bf16  (fused bucket spmm, LDS f32 acc)
//   h1w = h1 @ w2                     [N,128] bf16  (mfma gemm, K=128)
//   z   = relu(spmm(h1w) + b2)@wo+bo  [N]   fp32    (fused bucket spmm + dot)
// Edges partitioned once into 128-row buckets ({col | rowrel<<17, val} packed);
// spmm accumulates each bucket in a 64KB LDS tile via ds_add_f32 — no row sort.

#define HID 128
#define CHUNK_E 16384
#define RB 128               // rows per bucket
#define MAXBUCKET 800        // LDS table bound (N <= 102400)

typedef __attribute__((ext_vector_type(8))) short bf16x8;
typedef __attribute__((ext_vector_type(4))) float f32x4;

__device__ __forceinline__ ushort f2bf(float f) {
    union { float f; unsigned u; } v; v.f = f;
    unsigned r = v.u + 0x7fffu + ((v.u >> 16) & 1u);  // RNE
    return (ushort)(r >> 16);
}
__device__ __forceinline__ float bf2f(ushort u) {
    return __uint_as_float(((unsigned)u) << 16);
}

// ---------------- bucket histogram (per 16K-edge chunk) ----------------
__global__ __launch_bounds__(256) void bhist_kernel(const int* __restrict__ rows,
                                                    int* __restrict__ histT,
                                                    int E, int nbucket, int nchunk) {
    __shared__ int h[MAXBUCKET];
    const int t = threadIdx.x;
    const int c = blockIdx.x;
    for (int b = t; b < nbucket; b += 256) h[b] = 0;
    __syncthreads();
    const int estart = c * CHUNK_E;
    const int eend = min(estart + CHUNK_E, E);
    for (int e4 = estart + t * 4; e4 < eend; e4 += 1024) {
        if (e4 + 4 <= eend) {
            const int4 r4 = *reinterpret_cast<const int4*>(&rows[e4]);
            atomicAdd(&h[r4.x >> 7], 1);
            atomicAdd(&h[r4.y >> 7], 1);
            atomicAdd(&h[r4.z >> 7], 1);
            atomicAdd(&h[r4.w >> 7], 1);
        } else {
            for (int e = e4; e < eend; ++e) atomicAdd(&h[rows[e] >> 7], 1);
        }
    }
    __syncthreads();
    for (int b = t; b < nbucket; b += 256) histT[b * nchunk + c] = h[b];
}

// ---------------- coalesced 3-phase exclusive scan of histT[ntot] ----------------
__global__ __launch_bounds__(256) void bsum_kernel(const int* __restrict__ histT,
                                                   int* __restrict__ bsums, int ntot) {
    __shared__ int part[256];
    const int t = threadIdx.x;
    const int i0 = blockIdx.x * 512 + 2 * t;
    int a = (i0 < ntot) ? histT[i0] : 0;
    int b = (i0 + 1 < ntot) ? histT[i0 + 1] : 0;
    part[t] = a + b;
    __syncthreads();
    for (int off = 128; off > 0; off >>= 1) {
        if (t < off) part[t] += part[t + off];
        __syncthreads();
    }
    if (t == 0) bsums[blockIdx.x] = part[0];
}

__global__ __launch_bounds__(1024) void bscan_kernel(int* __restrict__ bsums, int nseg) {
    __shared__ int s[1024];
    const int t = threadIdx.x;
    int v = (t < nseg) ? bsums[t] : 0;
    s[t] = v;
    __syncthreads();
    for (int off = 1; off < 1024; off <<= 1) {
        int u = (t >= off) ? s[t - off] : 0;
        __syncthreads();
        s[t] += u;
        __syncthreads();
    }
    if (t < nseg) bsums[t] = s[t] - v;  // exclusive
}

__global__ __launch_bounds__(256) void bemit_kernel(int* __restrict__ histT,
                                                    const int* __restrict__ bsums, int ntot) {
    __shared__ int part[256];
    const int t = threadIdx.x;
    const int i0 = blockIdx.x * 512 + 2 * t;
    const int a = (i0 < ntot) ? histT[i0] : 0;
    const int b = (i0 + 1 < ntot) ? histT[i0 + 1] : 0;
    part[t] = a + b;
    __syncthreads();
    for (int off = 1; off < 256; off <<= 1) {
        int u = (t >= off) ? part[t - off] : 0;
        __syncthreads();
        part[t] += u;
        __syncthreads();
    }
    const int base = bsums[blockIdx.x] + part[t] - (a + b);
    if (i0 < ntot) histT[i0] = base;
    if (i0 + 1 < ntot) histT[i0 + 1] = base + a;
}

// ---------------- partition edges into bucket-contiguous runs ----------------
__global__ __launch_bounds__(256) void partition_kernel(const int* __restrict__ rows,
                                                        const int* __restrict__ cols,
                                                        const float* __restrict__ vals,
                                                        const int* __restrict__ baseT,
                                                        int2* __restrict__ bcv,
                                                        int E, int nbucket, int nchunk) {
    __shared__ int cur[MAXBUCKET];
    const int t = threadIdx.x;
    const int c = blockIdx.x;
    for (int b = t; b < nbucket; b += 256) cur[b] = baseT[b * nchunk + c];
    __syncthreads();
    const int estart = c * CHUNK_E;
    const int eend = min(estart + CHUNK_E, E);
    for (int e4 = estart + t * 4; e4 < eend; e4 += 1024) {
        if (e4 + 4 <= eend) {
            const int4 r4 = *reinterpret_cast<const int4*>(&rows[e4]);
            const int4 c4 = *reinterpret_cast<const int4*>(&cols[e4]);
            const float4 v4 = *reinterpret_cast<const float4*>(&vals[e4]);
            int p;
            p = atomicAdd(&cur[r4.x >> 7], 1);
            bcv[p] = make_int2(c4.x | ((r4.x & (RB - 1)) << 17), __float_as_int(v4.x));
            p = atomicAdd(&cur[r4.y >> 7], 1);
            bcv[p] = make_int2(c4.y | ((r4.y & (RB - 1)) << 17), __float_as_int(v4.y));
            p = atomicAdd(&cur[r4.z >> 7], 1);
            bcv[p] = make_int2(c4.z | ((r4.z & (RB - 1)) << 17), __float_as_int(v4.z));
            p = atomicAdd(&cur[r4.w >> 7], 1);
            bcv[p] = make_int2(c4.w | ((r4.w & (RB - 1)) << 17), __float_as_int(v4.w));
        } else {
            for (int e = e4; e < eend; ++e) {
                int r = rows[e];
                int p = atomicAdd(&cur[r >> 7], 1);
                bcv[p] = make_int2(cols[e] | ((r & (RB - 1)) << 17), __float_as_int(vals[e]));
            }
        }
    }
}

// ---------------- MFMA GEMM: C[N,128](bf16) = A[N,K] @ W[K,128] ----------------
// Block 256 thr = 4 waves; block tile 128 rows; wave tile 32 rows x 128 cols.
// W^T staged in LDS bf16 in 128-k phases (32 KB), XOR-swizzled for b128 reads.
template <int K, bool ABF16>
__global__ __launch_bounds__(256) void mfma_gemm(const void* __restrict__ Aptr,
                                                 const float* __restrict__ W,
                                                 ushort* __restrict__ C, int nrows) {
    constexpr int KH = 128;
    __shared__ __align__(16) ushort wt[128 * KH];
    const int t = threadIdx.x;
    const int lane = t & 63;
    const int wv = t >> 6;
    const int r = lane & 15;
    const int g = lane >> 4;
    const int row_base = blockIdx.x * 128 + wv * 32;
    const unsigned xorv = (unsigned)((r & 7) << 4);
    f32x4 acc[2][8] = {};

    for (int kh = 0; kh < K; kh += KH) {
        if (kh) __syncthreads();
        // stage W^T[kh..kh+KH) as bf16, swizzled: byte ^= (col&7)<<4
        for (int idx = t; idx < KH * 32; idx += 256) {
            const int c4 = (idx & 31) << 2;
            const int k = idx >> 5;
            const float4 w4 = *reinterpret_cast<const float4*>(&W[(kh + k) * 128 + c4]);
            const float wf[4] = {w4.x, w4.y, w4.z, w4.w};
            #pragma unroll
            for (int j = 0; j < 4; ++j) {
                const int c = c4 + j;
                const unsigned byteoff = (unsigned)(((c * KH + k) * 2) ^ ((c & 7) << 4));
                *reinterpret_cast<ushort*>(reinterpret_cast<char*>(wt) + byteoff) = f2bf(wf[j]);
            }
        }
        __syncthreads();

        for (int s = 0; s < KH / 32; ++s) {
            const int kbg = kh + s * 32 + g * 8;  // global k for A
            const int kbl = s * 32 + g * 8;       // LDS-local k
            bf16x8 a[2];
            #pragma unroll
            for (int f = 0; f < 2; ++f) {
                int row = row_base + f * 16 + r;
                if (row >= nrows) row = nrows - 1;
                if (ABF16) {
                    a[f] = *reinterpret_cast<const bf16x8*>(
                        (const ushort*)Aptr + (size_t)row * K + kbg);
                } else {
                    const float* Af = (const float*)Aptr + (size_t)row * K + kbg;
                    const float4 v0 = *reinterpret_cast<const float4*>(Af);
                    const float4 v1 = *reinterpret_cast<const float4*>(Af + 4);
                    bf16x8 av;
                    av[0] = (short)f2bf(v0.x); av[1] = (short)f2bf(v0.y);
                    av[2] = (short)f2bf(v0.z); av[3] = (short)f2bf(v0.w);
                    av[4] = (short)f2bf(v1.x); av[5] = (short)f2bf(v1.y);
                    av[6] = (short)f2bf(v1.z); av[7] = (short)f2bf(v1.w);
                    a[f] = av;
                }
            }
            #pragma unroll
            for (int c = 0; c < 8; ++c) {
                const unsigned boff = ((unsigned)(((c * 16 + r) * KH + kbl) * 2)) ^ xorv;
                const bf16x8 b = *reinterpret_cast<const bf16x8*>(
                    reinterpret_cast<char*>(wt) + boff);
                acc[0][c] = __builtin_amdgcn_mfma_f32_16x16x32_bf16(a[0], b, acc[0][c], 0, 0, 0);
                acc[1][c] = __builtin_amdgcn_mfma_f32_16x16x32_bf16(a[1], b, acc[1][c], 0, 0, 0);
            }
        }
    }
    // epilogue: C/D map col=lane&15, row=4*(lane>>4)+j (m89-verified)
    #pragma unroll
    for (int f = 0; f < 2; ++f) {
        #pragma unroll
        for (int j = 0; j < 4; ++j) {
            const int row = row_base + f * 16 + g * 4 + j;
            if (row < nrows) {
                #pragma unroll
                for (int c = 0; c < 8; ++c) {
                    C[(size_t)row * HID + c * 16 + r] = f2bf(acc[f][c][j]);
                }
            }
        }
    }
}

// ---------------- fused bucket SpMM: LDS f32 acc, bf16 gather ----------------
// One block per 128-row bucket. Wave-edge: gather X[col] (256B), ds_add into acc.
template <bool FINAL>
__global__ __launch_bounds__(256) void spmm_fused(const int* __restrict__ histT,
                                                  const int2* __restrict__ bcv,
                                                  const ushort* __restrict__ X,
                                                  const float* __restrict__ bias,
                                                  const float* __restrict__ wo,
                                                  const float* __restrict__ bo,
                                                  void* __restrict__ out,
                                                  int N, int E, int nchunk, int nbucket) {
    __shared__ float acc[RB * HID];  // 64 KB
    const int t = threadIdx.x;
    const int wv = t >> 6;
    const int lane = t & 63;
    const int b = blockIdx.x;
    const int rowbase = b << 7;
    #pragma unroll
    for (int i = 0; i < (RB * HID / 4) / 256; ++i)
        reinterpret_cast<float4*>(acc)[t + i * 256] = make_float4(0.f, 0.f, 0.f, 0.f);
    __syncthreads();

    const int bstart = histT[b * nchunk];
    const int bend = (b + 1 < nbucket) ? histT[(b + 1) * nchunk] : E;
    const int f0 = lane * 2;

    for (int e8 = bstart + wv * 8; e8 < bend; e8 += 32) {
        const int cnt = min(8, bend - e8);
        if (cnt == 8) {
            int2 ev[8];
            #pragma unroll
            for (int i = 0; i < 8; ++i) ev[i] = bcv[e8 + i];
            unsigned xv[8];
            #pragma unroll
            for (int i = 0; i < 8; ++i)
                xv[i] = *reinterpret_cast<const unsigned*>(
                    &X[(size_t)(ev[i].x & 0x1FFFF) * HID + f0]);
            #pragma unroll
            for (int i = 0; i < 8; ++i) {
                const float v = __int_as_float(ev[i].y);
                const int rr = (ev[i].x >> 17) & (RB - 1);
                float* ap = &acc[rr * HID + f0];
                atomicAdd(ap, v * bf2f((ushort)(xv[i] & 0xffffu)));
                atomicAdd(ap + 1, v * bf2f((ushort)(xv[i] >> 16)));
            }
        } else {
            for (int j = 0; j < cnt; ++j) {
                const int2 ev = bcv[e8 + j];
                const unsigned xu = *reinterpret_cast<const unsigned*>(
                    &X[(size_t)(ev.x & 0x1FFFF) * HID + f0]);
                const float v = __int_as_float(ev.y);
                const int rr = (ev.x >> 17) & (RB - 1);
                float* ap = &acc[rr * HID + f0];
                atomicAdd(ap, v * bf2f((ushort)(xu & 0xffffu)));
                atomicAdd(ap + 1, v * bf2f((ushort)(xu >> 16)));
            }
        }
    }
    __syncthreads();

    if (!FINAL) {
        // h = relu(acc + bias) -> bf16 packed, coalesced u32 stores
        #pragma unroll
        for (int it = 0; it < (RB * 64) / 256; ++it) {
            const int flat = t + it * 256;
            const int row = flat >> 6;
            const int fp = flat & 63;
            if (rowbase + row < N) {
                const float hx = fmaxf(acc[row * HID + 2 * fp] + bias[2 * fp], 0.f);
                const float hy = fmaxf(acc[row * HID + 2 * fp + 1] + bias[2 * fp + 1], 0.f);
                reinterpret_cast<unsigned*>(out)[(size_t)(rowbase + row) * 64 + fp] =
                    (unsigned)f2bf(hx) | ((unsigned)f2bf(hy) << 16);
            }
        }
    } else {
        // z[row] = relu(acc + b2) . wo + bo ; 2 threads per row, row-rotated reads
        const int row = t >> 1;
        const int half = t & 1;
        float p = 0.f;
        #pragma unroll
        for (int i = 0; i < 64; ++i) {
            const int f = ((i + row) & 63) * 2 + half;
            p += fmaxf(acc[row * HID + f] + bias[f], 0.f) * wo[f];
        }
        p += __shfl_xor(p, 1, 64);
        if (half == 0 && rowbase + row < N)
            reinterpret_cast<float*>(out)[rowbase + row] = p + bo[0];
    }
}

extern "C" void kernel_launch(void* const* d_in, const int* in_sizes, int n_in,
                              void* d_out, int out_size, void* d_ws, size_t ws_size,
                              hipStream_t stream) {
    const float* x        = (const float*)d_in[0];
    const int*   e_rows   = (const int*)d_in[1];
    const int*   e_cols   = (const int*)d_in[2];
    const float* e_vals   = (const float*)d_in[3];
    const float* w1       = (const float*)d_in[4];
    const float* b1       = (const float*)d_in[5];
    const float* w2       = (const float*)d_in[6];
    const float* b2       = (const float*)d_in[7];
    const float* wo       = (const float*)d_in[8];
    const float* bo       = (const float*)d_in[9];
    float* z = (float*)d_out;

    const int IN_DIM = 256;
    const int N = in_sizes[0] / IN_DIM;
    const int E = in_sizes[1];
    const int NCHUNK = (E + CHUNK_E - 1) / CHUNK_E;
    const int NBUCKET = (N + RB - 1) / RB;
    const int NTOT = NBUCKET * NCHUNK;
    const int NSEG = (NTOT + 511) / 512;  // must be <= 1024

    size_t off = 0;
    auto alloc = [&](size_t bytes) {
        void* p = (char*)d_ws + off;
        off += (bytes + 255) & ~(size_t)255;
        return p;
    };
    ushort* bufA  = (ushort*)alloc((size_t)N * HID * 2);   // xw, later h1w (bf16)
    ushort* bufB  = (ushort*)alloc((size_t)N * HID * 2);   // h1 (bf16)
    int*   histT  = (int*)alloc((size_t)NTOT * 4);         // -> (bucket,chunk) bases
    int*   bsums  = (int*)alloc((size_t)NSEG * 4);
    int2*  bcv    = (int2*)alloc((size_t)E * 8);
    (void)ws_size;

    // ---- bucket partition ----
    bhist_kernel<<<NCHUNK, 256, 0, stream>>>(e_rows, histT, E, NBUCKET, NCHUNK);
    bsum_kernel<<<NSEG, 256, 0, stream>>>(histT, bsums, NTOT);
    bscan_kernel<<<1, 1024, 0, stream>>>(bsums, NSEG);
    bemit_kernel<<<NSEG, 256, 0, stream>>>(histT, bsums, NTOT);
    partition_kernel<<<NCHUNK, 256, 0, stream>>>(e_rows, e_cols, e_vals, histT, bcv, E, NBUCKET, NCHUNK);

    const int gemm_grid = (N + 127) / 128;
    // ---- layer 1 ----
    mfma_gemm<256, false><<<gemm_grid, 256, 0, stream>>>(x, w1, bufA, N);
    spmm_fused<false><<<NBUCKET, 256, 0, stream>>>(histT, bcv, bufA, b1, nullptr, nullptr, bufB, N, E, NCHUNK, NBUCKET);

    // ---- layer 2 + output ----
    mfma_gemm<128, true><<<gemm_grid, 256, 0, stream>>>(bufB, w2, bufA, N);
    spmm_fused<true><<<NBUCKET, 256, 0, stream>>>(histT, bcv, bufA, b2, wo, bo, z, N, E, NCHUNK, NBUCKET);
}

// Round 6
// 638.260 us; speedup vs baseline: 8.8283x; 8.8283x over previous
//
#include <hip/hip_runtime.h>
#include <hip/hip_bf16.h>

// SimpleSAGE on MI355X — bf16 features, MFMA GEMMs, row-sorted CSR spmm.
//   xw  = x @ w1                      [N,128] bf16  (mfma gemm, K=256)
//   h1  = relu(spmm(xw) + b1)         [N,128] bf16  (row-per-wave spmm, fp32 acc)
//   h1w = h1 @ w2                     [N,128] bf16  (mfma gemm, K=128)
//   z   = relu(spmm(h1w) + b2)@wo+bo  [N]   fp32
// CSR built per-call: radix partition to 512-row buckets (chunked LDS cursors,
// 3-phase coalesced scan) -> finalize (per-bucket row sort in L2-warm window).

#define HID 128
#define CHUNK_E 16384

typedef __attribute__((ext_vector_type(8))) short bf16x8;
typedef __attribute__((ext_vector_type(4))) float f32x4;

__device__ __forceinline__ ushort f2bf(float f) {
    union { float f; unsigned u; } v; v.f = f;
    unsigned r = v.u + 0x7fffu + ((v.u >> 16) & 1u);  // RNE
    return (ushort)(r >> 16);
}
__device__ __forceinline__ float bf2f(ushort u) {
    return __uint_as_float(((unsigned)u) << 16);
}

// ---------------- bucket histogram (bucket = row>>9, per 16K-edge chunk) ----------
__global__ __launch_bounds__(256) void bhist_kernel(const int* __restrict__ rows,
                                                    int* __restrict__ histT,
                                                    int E, int nbucket, int nchunk) {
    __shared__ int h[512];
    const int t = threadIdx.x;
    const int c = blockIdx.x;
    for (int b = t; b < nbucket; b += 256) h[b] = 0;
    __syncthreads();
    const int estart = c * CHUNK_E;
    const int eend = min(estart + CHUNK_E, E);
    for (int e4 = estart + t * 4; e4 < eend; e4 += 1024) {
        if (e4 + 4 <= eend) {
            const int4 r4 = *reinterpret_cast<const int4*>(&rows[e4]);
            atomicAdd(&h[r4.x >> 9], 1);
            atomicAdd(&h[r4.y >> 9], 1);
            atomicAdd(&h[r4.z >> 9], 1);
            atomicAdd(&h[r4.w >> 9], 1);
        } else {
            for (int e = e4; e < eend; ++e) atomicAdd(&h[rows[e] >> 9], 1);
        }
    }
    __syncthreads();
    for (int b = t; b < nbucket; b += 256) histT[b * nchunk + c] = h[b];
}

// ---------------- coalesced 3-phase exclusive scan of histT[ntot] ----------------
__global__ __launch_bounds__(256) void bsum_kernel(const int* __restrict__ histT,
                                                   int* __restrict__ bsums, int ntot) {
    __shared__ int part[256];
    const int t = threadIdx.x;
    const int i0 = blockIdx.x * 512 + 2 * t;
    int a = (i0 < ntot) ? histT[i0] : 0;
    int b = (i0 + 1 < ntot) ? histT[i0 + 1] : 0;
    part[t] = a + b;
    __syncthreads();
    for (int off = 128; off > 0; off >>= 1) {
        if (t < off) part[t] += part[t + off];
        __syncthreads();
    }
    if (t == 0) bsums[blockIdx.x] = part[0];
}

__global__ __launch_bounds__(1024) void bscan_kernel(int* __restrict__ bsums, int nseg,
                                                     int* __restrict__ rowptr, int n, int E) {
    __shared__ int s[1024];
    const int t = threadIdx.x;
    int v = (t < nseg) ? bsums[t] : 0;
    s[t] = v;
    __syncthreads();
    for (int off = 1; off < 1024; off <<= 1) {
        int u = (t >= off) ? s[t - off] : 0;
        __syncthreads();
        s[t] += u;
        __syncthreads();
    }
    if (t < nseg) bsums[t] = s[t] - v;  // exclusive
    if (t == 0) rowptr[n] = E;
}

__global__ __launch_bounds__(256) void bemit_kernel(int* __restrict__ histT,
                                                    const int* __restrict__ bsums, int ntot) {
    __shared__ int part[256];
    const int t = threadIdx.x;
    const int i0 = blockIdx.x * 512 + 2 * t;
    const int a = (i0 < ntot) ? histT[i0] : 0;
    const int b = (i0 + 1 < ntot) ? histT[i0 + 1] : 0;
    part[t] = a + b;
    __syncthreads();
    for (int off = 1; off < 256; off <<= 1) {
        int u = (t >= off) ? part[t - off] : 0;
        __syncthreads();
        part[t] += u;
        __syncthreads();
    }
    const int base = bsums[blockIdx.x] + part[t] - (a + b);
    if (i0 < ntot) histT[i0] = base;
    if (i0 + 1 < ntot) histT[i0 + 1] = base + a;
}

// ---------------- partition edges into bucket-contiguous runs ----------------
__global__ __launch_bounds__(256) void partition_kernel(const int* __restrict__ rows,
                                                        const int* __restrict__ cols,
                                                        const float* __restrict__ vals,
                                                        const int* __restrict__ baseT,
                                                        int2* __restrict__ bcv,
                                                        int E, int nbucket, int nchunk) {
    __shared__ int cur[512];
    const int t = threadIdx.x;
    const int c = blockIdx.x;
    for (int b = t; b < nbucket; b += 256) cur[b] = baseT[b * nchunk + c];
    __syncthreads();
    const int estart = c * CHUNK_E;
    const int eend = min(estart + CHUNK_E, E);
    for (int e4 = estart + t * 4; e4 < eend; e4 += 1024) {
        if (e4 + 4 <= eend) {
            const int4 r4 = *reinterpret_cast<const int4*>(&rows[e4]);
            const int4 c4 = *reinterpret_cast<const int4*>(&cols[e4]);
            const float4 v4 = *reinterpret_cast<const float4*>(&vals[e4]);
            int p;
            p = atomicAdd(&cur[r4.x >> 9], 1);
            bcv[p] = make_int2(c4.x | ((r4.x & 511) << 17), __float_as_int(v4.x));
            p = atomicAdd(&cur[r4.y >> 9], 1);
            bcv[p] = make_int2(c4.y | ((r4.y & 511) << 17), __float_as_int(v4.y));
            p = atomicAdd(&cur[r4.z >> 9], 1);
            bcv[p] = make_int2(c4.z | ((r4.z & 511) << 17), __float_as_int(v4.z));
            p = atomicAdd(&cur[r4.w >> 9], 1);
            bcv[p] = make_int2(c4.w | ((r4.w & 511) << 17), __float_as_int(v4.w));
        } else {
            for (int e = e4; e < eend; ++e) {
                int r = rows[e];
                int p = atomicAdd(&cur[r >> 9], 1);
                bcv[p] = make_int2(cols[e] | ((r & 511) << 17), __float_as_int(vals[e]));
            }
        }
    }
}

// ---------------- finalize: per-bucket row sort -> rowptr + epair ----------------
__global__ __launch_bounds__(256) void finalize_kernel(const int2* __restrict__ bcv,
                                                       const int* __restrict__ baseT,
                                                       int* __restrict__ rowptr,
                                                       int2* __restrict__ epair,
                                                       int N, int E, int nchunk, int nbucket) {
    __shared__ int cnt[512];
    __shared__ int part[256];
    const int t = threadIdx.x;
    const int b = blockIdx.x;
    const int rowbase = b << 9;
    const int nrows_b = min(512, N - rowbase);
    const int bstart = baseT[b * nchunk];
    const int bend = (b + 1 < nbucket) ? baseT[(b + 1) * nchunk] : E;
    cnt[t] = 0;
    cnt[t + 256] = 0;
    __syncthreads();
    for (int e = bstart + t; e < bend; e += 256) {
        const int w0 = reinterpret_cast<const int*>(bcv)[2 * e];
        atomicAdd(&cnt[w0 >> 17], 1);
    }
    __syncthreads();
    const int a0 = cnt[2 * t];
    const int a1 = cnt[2 * t + 1];
    part[t] = a0 + a1;
    __syncthreads();
    for (int off = 1; off < 256; off <<= 1) {
        int u = (t >= off) ? part[t - off] : 0;
        __syncthreads();
        part[t] += u;
        __syncthreads();
    }
    const int excl = part[t] - (a0 + a1);
    cnt[2 * t] = bstart + excl;
    cnt[2 * t + 1] = bstart + excl + a0;
    if (2 * t < nrows_b) rowptr[rowbase + 2 * t] = bstart + excl;
    if (2 * t + 1 < nrows_b) rowptr[rowbase + 2 * t + 1] = bstart + excl + a0;
    __syncthreads();
    for (int e = bstart + t; e < bend; e += 256) {
        const int2 w = bcv[e];
        const int p = atomicAdd(&cnt[w.x >> 17], 1);
        epair[p] = make_int2(w.x & 0x1FFFF, w.y);
    }
}

// ---------------- MFMA GEMM: C[N,128](bf16) = A[N,K] @ W[K,128] ----------------
// Block 256 thr = 4 waves; block tile 128 rows; wave tile 32 rows x 128 cols.
// W^T staged in LDS bf16 in 128-k phases (32 KB), XOR-swizzled for b128 reads.
template <int K, bool ABF16>
__global__ __launch_bounds__(256) void mfma_gemm(const void* __restrict__ Aptr,
                                                 const float* __restrict__ W,
                                                 ushort* __restrict__ C, int nrows) {
    constexpr int KH = 128;
    __shared__ __align__(16) ushort wt[128 * KH];
    const int t = threadIdx.x;
    const int lane = t & 63;
    const int wv = t >> 6;
    const int r = lane & 15;
    const int g = lane >> 4;
    const int row_base = blockIdx.x * 128 + wv * 32;
    const unsigned xorv = (unsigned)((r & 7) << 4);
    f32x4 acc[2][8] = {};

    for (int kh = 0; kh < K; kh += KH) {
        if (kh) __syncthreads();
        for (int idx = t; idx < KH * 32; idx += 256) {
            const int c4 = (idx & 31) << 2;
            const int k = idx >> 5;
            const float4 w4 = *reinterpret_cast<const float4*>(&W[(kh + k) * 128 + c4]);
            const float wf[4] = {w4.x, w4.y, w4.z, w4.w};
            #pragma unroll
            for (int j = 0; j < 4; ++j) {
                const int c = c4 + j;
                const unsigned byteoff = (unsigned)(((c * KH + k) * 2) ^ ((c & 7) << 4));
                *reinterpret_cast<ushort*>(reinterpret_cast<char*>(wt) + byteoff) = f2bf(wf[j]);
            }
        }
        __syncthreads();

        for (int s = 0; s < KH / 32; ++s) {
            const int kbg = kh + s * 32 + g * 8;
            const int kbl = s * 32 + g * 8;
            bf16x8 a[2];
            #pragma unroll
            for (int f = 0; f < 2; ++f) {
                int row = row_base + f * 16 + r;
                if (row >= nrows) row = nrows - 1;
                if (ABF16) {
                    a[f] = *reinterpret_cast<const bf16x8*>(
                        (const ushort*)Aptr + (size_t)row * K + kbg);
                } else {
                    const float* Af = (const float*)Aptr + (size_t)row * K + kbg;
                    const float4 v0 = *reinterpret_cast<const float4*>(Af);
                    const float4 v1 = *reinterpret_cast<const float4*>(Af + 4);
                    bf16x8 av;
                    av[0] = (short)f2bf(v0.x); av[1] = (short)f2bf(v0.y);
                    av[2] = (short)f2bf(v0.z); av[3] = (short)f2bf(v0.w);
                    av[4] = (short)f2bf(v1.x); av[5] = (short)f2bf(v1.y);
                    av[6] = (short)f2bf(v1.z); av[7] = (short)f2bf(v1.w);
                    a[f] = av;
                }
            }
            #pragma unroll
            for (int c = 0; c < 8; ++c) {
                const unsigned boff = ((unsigned)(((c * 16 + r) * KH + kbl) * 2)) ^ xorv;
                const bf16x8 b = *reinterpret_cast<const bf16x8*>(
                    reinterpret_cast<char*>(wt) + boff);
                acc[0][c] = __builtin_amdgcn_mfma_f32_16x16x32_bf16(a[0], b, acc[0][c], 0, 0, 0);
                acc[1][c] = __builtin_amdgcn_mfma_f32_16x16x32_bf16(a[1], b, acc[1][c], 0, 0, 0);
            }
        }
    }
    #pragma unroll
    for (int f = 0; f < 2; ++f) {
        #pragma unroll
        for (int j = 0; j < 4; ++j) {
            const int row = row_base + f * 16 + g * 4 + j;
            if (row < nrows) {
                #pragma unroll
                for (int c = 0; c < 8; ++c) {
                    C[(size_t)row * HID + c * 16 + r] = f2bf(acc[f][c][j]);
                }
            }
        }
    }
}

// ---------------- CSR SpMM (bf16 gather), one wave per row, 16-deep MLP ----------
template <bool FINAL>
__global__ __launch_bounds__(256) void spmm_kernel(const int* __restrict__ row_ptr,
                                                   const int2* __restrict__ epair,
                                                   const ushort* __restrict__ X,
                                                   const float* __restrict__ bias,
                                                   const float* __restrict__ wo,
                                                   const float* __restrict__ bo,
                                                   void* __restrict__ out, int nrows) {
    const int wave = threadIdx.x >> 6;
    const int lane = threadIdx.x & 63;
    const int row = blockIdx.x * 4 + wave;
    if (row >= nrows) return;
    const int e0 = row_ptr[row];
    const int e1 = row_ptr[row + 1];
    float ax = 0.f, ay = 0.f;
    int e = e0;
    for (; e + 16 <= e1; e += 16) {
        int2 ev[16];
        #pragma unroll
        for (int i = 0; i < 16; ++i) ev[i] = epair[e + i];
        unsigned xv[16];
        #pragma unroll
        for (int i = 0; i < 16; ++i)
            xv[i] = *reinterpret_cast<const unsigned*>(&X[(size_t)ev[i].x * HID + lane * 2]);
        #pragma unroll
        for (int i = 0; i < 16; ++i) {
            const float v = __int_as_float(ev[i].y);
            ax += v * bf2f((ushort)(xv[i] & 0xffffu));
            ay += v * bf2f((ushort)(xv[i] >> 16));
        }
    }
    for (; e < e1; ++e) {
        const int2 evt = epair[e];
        const unsigned xu = *reinterpret_cast<const unsigned*>(&X[(size_t)evt.x * HID + lane * 2]);
        const float v = __int_as_float(evt.y);
        ax += v * bf2f((ushort)(xu & 0xffffu));
        ay += v * bf2f((ushort)(xu >> 16));
    }
    const float hx = fmaxf(ax + bias[lane * 2], 0.f);
    const float hy = fmaxf(ay + bias[lane * 2 + 1], 0.f);
    if (!FINAL) {
        const unsigned packed = (unsigned)f2bf(hx) | ((unsigned)f2bf(hy) << 16);
        reinterpret_cast<unsigned*>(out)[(size_t)row * (HID / 2) + lane] = packed;
    } else {
        float p = hx * wo[lane * 2] + hy * wo[lane * 2 + 1];
        #pragma unroll
        for (int off = 32; off > 0; off >>= 1) p += __shfl_down(p, off, 64);
        if (lane == 0) reinterpret_cast<float*>(out)[row] = p + bo[0];
    }
}

extern "C" void kernel_launch(void* const* d_in, const int* in_sizes, int n_in,
                              void* d_out, int out_size, void* d_ws, size_t ws_size,
                              hipStream_t stream) {
    const float* x        = (const float*)d_in[0];
    const int*   e_rows   = (const int*)d_in[1];
    const int*   e_cols   = (const int*)d_in[2];
    const float* e_vals   = (const float*)d_in[3];
    const float* w1       = (const float*)d_in[4];
    const float* b1       = (const float*)d_in[5];
    const float* w2       = (const float*)d_in[6];
    const float* b2       = (const float*)d_in[7];
    const float* wo       = (const float*)d_in[8];
    const float* bo       = (const float*)d_in[9];
    float* z = (float*)d_out;

    const int IN_DIM = 256;
    const int N = in_sizes[0] / IN_DIM;
    const int E = in_sizes[1];
    const int NCHUNK = (E + CHUNK_E - 1) / CHUNK_E;
    const int NBUCKET = (N + 511) >> 9;
    const int NTOT = NBUCKET * NCHUNK;
    const int NSEG = (NTOT + 511) / 512;  // must be <= 1024

    size_t off = 0;
    auto alloc = [&](size_t bytes) {
        void* p = (char*)d_ws + off;
        off += (bytes + 255) & ~(size_t)255;
        return p;
    };
    ushort* bufA  = (ushort*)alloc((size_t)N * HID * 2);   // xw, later h1w (bf16)
    ushort* bufB  = (ushort*)alloc((size_t)N * HID * 2);   // h1 (bf16)
    int*   rowptr = (int*)alloc((size_t)(N + 1) * 4);
    int*   histT  = (int*)alloc((size_t)NTOT * 4);
    int*   bsums  = (int*)alloc((size_t)NSEG * 4);
    int2*  epair  = (int2*)alloc((size_t)E * 8);
    int2*  bcv    = (int2*)alloc((size_t)E * 8);
    (void)ws_size;

    // ---- CSR build ----
    bhist_kernel<<<NCHUNK, 256, 0, stream>>>(e_rows, histT, E, NBUCKET, NCHUNK);
    bsum_kernel<<<NSEG, 256, 0, stream>>>(histT, bsums, NTOT);
    bscan_kernel<<<1, 1024, 0, stream>>>(bsums, NSEG, rowptr, N, E);
    bemit_kernel<<<NSEG, 256, 0, stream>>>(histT, bsums, NTOT);
    partition_kernel<<<NCHUNK, 256, 0, stream>>>(e_rows, e_cols, e_vals, histT, bcv, E, NBUCKET, NCHUNK);
    finalize_kernel<<<NBUCKET, 256, 0, stream>>>(bcv, histT, rowptr, epair, N, E, NCHUNK, NBUCKET);

    const int gemm_grid = (N + 127) / 128;
    // ---- layer 1 ----
    mfma_gemm<256, false><<<gemm_grid, 256, 0, stream>>>(x, w1, bufA, N);
    spmm_kernel<false><<<(N + 3) / 4, 256, 0, stream>>>(rowptr, epair, bufA, b1, nullptr, nullptr, bufB, N);

    // ---- layer 2 + output ----
    mfma_gemm<128, true><<<gemm_grid, 256, 0, stream>>>(bufB, w2, bufA, N);
    spmm_kernel<true><<<(N + 3) / 4, 256, 0, stream>>>(rowptr, epair, bufA, b2, wo, bo, z, N);
}

// Round 7
// 628.238 us; speedup vs baseline: 8.9691x; 1.0160x over previous
//
#include <hip/hip_runtime.h>
#include <hip/hip_bf16.h>

// SimpleSAGE on MI355X — bf16 features, MFMA GEMMs, row-sorted CSR spmm.
//   xw  = x @ w1                      [N,128] bf16  (mfma gemm, K=256)
//   h1  = relu(spmm(xw) + b1)         [N,128] bf16  (row-per-wave spmm, fp32 acc)
//   h1w = h1 @ w2                     [N,128] bf16  (mfma gemm, K=128)
//   z   = relu(spmm(h1w) + b2)@wo+bo  [N]   fp32
// CSR built per-call: radix partition to 512-row buckets -> per-bucket row sort.
// spmm: 8-deep parallel gather batches (incl. masked tail batch), nontemporal
// edge-stream loads / output stores so gathered X stays L2-resident.

#define HID 128
#define CHUNK_E 16384

typedef __attribute__((ext_vector_type(8))) short bf16x8;
typedef __attribute__((ext_vector_type(4))) float f32x4;

__device__ __forceinline__ ushort f2bf(float f) {
    union { float f; unsigned u; } v; v.f = f;
    unsigned r = v.u + 0x7fffu + ((v.u >> 16) & 1u);  // RNE
    return (ushort)(r >> 16);
}
__device__ __forceinline__ float bf2f(ushort u) {
    return __uint_as_float(((unsigned)u) << 16);
}

// ---------------- bucket histogram (bucket = row>>9, per 16K-edge chunk) ----------
__global__ __launch_bounds__(256) void bhist_kernel(const int* __restrict__ rows,
                                                    int* __restrict__ histT,
                                                    int E, int nbucket, int nchunk) {
    __shared__ int h[512];
    const int t = threadIdx.x;
    const int c = blockIdx.x;
    for (int b = t; b < nbucket; b += 256) h[b] = 0;
    __syncthreads();
    const int estart = c * CHUNK_E;
    const int eend = min(estart + CHUNK_E, E);
    for (int e4 = estart + t * 4; e4 < eend; e4 += 1024) {
        if (e4 + 4 <= eend) {
            const int4 r4 = *reinterpret_cast<const int4*>(&rows[e4]);
            atomicAdd(&h[r4.x >> 9], 1);
            atomicAdd(&h[r4.y >> 9], 1);
            atomicAdd(&h[r4.z >> 9], 1);
            atomicAdd(&h[r4.w >> 9], 1);
        } else {
            for (int e = e4; e < eend; ++e) atomicAdd(&h[rows[e] >> 9], 1);
        }
    }
    __syncthreads();
    for (int b = t; b < nbucket; b += 256) histT[b * nchunk + c] = h[b];
}

// ---------------- coalesced 3-phase exclusive scan of histT[ntot] ----------------
__global__ __launch_bounds__(256) void bsum_kernel(const int* __restrict__ histT,
                                                   int* __restrict__ bsums, int ntot) {
    __shared__ int part[256];
    const int t = threadIdx.x;
    const int i0 = blockIdx.x * 512 + 2 * t;
    int a = (i0 < ntot) ? histT[i0] : 0;
    int b = (i0 + 1 < ntot) ? histT[i0 + 1] : 0;
    part[t] = a + b;
    __syncthreads();
    for (int off = 128; off > 0; off >>= 1) {
        if (t < off) part[t] += part[t + off];
        __syncthreads();
    }
    if (t == 0) bsums[blockIdx.x] = part[0];
}

__global__ __launch_bounds__(1024) void bscan_kernel(int* __restrict__ bsums, int nseg,
                                                     int* __restrict__ rowptr, int n, int E) {
    __shared__ int s[1024];
    const int t = threadIdx.x;
    int v = (t < nseg) ? bsums[t] : 0;
    s[t] = v;
    __syncthreads();
    for (int off = 1; off < 1024; off <<= 1) {
        int u = (t >= off) ? s[t - off] : 0;
        __syncthreads();
        s[t] += u;
        __syncthreads();
    }
    if (t < nseg) bsums[t] = s[t] - v;  // exclusive
    if (t == 0) rowptr[n] = E;
}

__global__ __launch_bounds__(256) void bemit_kernel(int* __restrict__ histT,
                                                    const int* __restrict__ bsums, int ntot) {
    __shared__ int part[256];
    const int t = threadIdx.x;
    const int i0 = blockIdx.x * 512 + 2 * t;
    const int a = (i0 < ntot) ? histT[i0] : 0;
    const int b = (i0 + 1 < ntot) ? histT[i0 + 1] : 0;
    part[t] = a + b;
    __syncthreads();
    for (int off = 1; off < 256; off <<= 1) {
        int u = (t >= off) ? part[t - off] : 0;
        __syncthreads();
        part[t] += u;
        __syncthreads();
    }
    const int base = bsums[blockIdx.x] + part[t] - (a + b);
    if (i0 < ntot) histT[i0] = base;
    if (i0 + 1 < ntot) histT[i0 + 1] = base + a;
}

// ---------------- partition edges into bucket-contiguous runs ----------------
__global__ __launch_bounds__(256) void partition_kernel(const int* __restrict__ rows,
                                                        const int* __restrict__ cols,
                                                        const float* __restrict__ vals,
                                                        const int* __restrict__ baseT,
                                                        int2* __restrict__ bcv,
                                                        int E, int nbucket, int nchunk) {
    __shared__ int cur[512];
    const int t = threadIdx.x;
    const int c = blockIdx.x;
    for (int b = t; b < nbucket; b += 256) cur[b] = baseT[b * nchunk + c];
    __syncthreads();
    const int estart = c * CHUNK_E;
    const int eend = min(estart + CHUNK_E, E);
    for (int e4 = estart + t * 4; e4 < eend; e4 += 1024) {
        if (e4 + 4 <= eend) {
            const int4 r4 = *reinterpret_cast<const int4*>(&rows[e4]);
            const int4 c4 = *reinterpret_cast<const int4*>(&cols[e4]);
            const float4 v4 = *reinterpret_cast<const float4*>(&vals[e4]);
            int p;
            p = atomicAdd(&cur[r4.x >> 9], 1);
            bcv[p] = make_int2(c4.x | ((r4.x & 511) << 17), __float_as_int(v4.x));
            p = atomicAdd(&cur[r4.y >> 9], 1);
            bcv[p] = make_int2(c4.y | ((r4.y & 511) << 17), __float_as_int(v4.y));
            p = atomicAdd(&cur[r4.z >> 9], 1);
            bcv[p] = make_int2(c4.z | ((r4.z & 511) << 17), __float_as_int(v4.z));
            p = atomicAdd(&cur[r4.w >> 9], 1);
            bcv[p] = make_int2(c4.w | ((r4.w & 511) << 17), __float_as_int(v4.w));
        } else {
            for (int e = e4; e < eend; ++e) {
                int r = rows[e];
                int p = atomicAdd(&cur[r >> 9], 1);
                bcv[p] = make_int2(cols[e] | ((r & 511) << 17), __float_as_int(vals[e]));
            }
        }
    }
}

// ---------------- finalize: per-bucket row sort -> rowptr + epair ----------------
__global__ __launch_bounds__(256) void finalize_kernel(const int2* __restrict__ bcv,
                                                       const int* __restrict__ baseT,
                                                       int* __restrict__ rowptr,
                                                       int2* __restrict__ epair,
                                                       int N, int E, int nchunk, int nbucket) {
    __shared__ int cnt[512];
    __shared__ int part[256];
    const int t = threadIdx.x;
    const int b = blockIdx.x;
    const int rowbase = b << 9;
    const int nrows_b = min(512, N - rowbase);
    const int bstart = baseT[b * nchunk];
    const int bend = (b + 1 < nbucket) ? baseT[(b + 1) * nchunk] : E;
    cnt[t] = 0;
    cnt[t + 256] = 0;
    __syncthreads();
    for (int e = bstart + t; e < bend; e += 256) {
        const int w0 = __builtin_nontemporal_load(reinterpret_cast<const int*>(bcv) + 2 * e);
        atomicAdd(&cnt[w0 >> 17], 1);
    }
    __syncthreads();
    const int a0 = cnt[2 * t];
    const int a1 = cnt[2 * t + 1];
    part[t] = a0 + a1;
    __syncthreads();
    for (int off = 1; off < 256; off <<= 1) {
        int u = (t >= off) ? part[t - off] : 0;
        __syncthreads();
        part[t] += u;
        __syncthreads();
    }
    const int excl = part[t] - (a0 + a1);
    cnt[2 * t] = bstart + excl;
    cnt[2 * t + 1] = bstart + excl + a0;
    if (2 * t < nrows_b) rowptr[rowbase + 2 * t] = bstart + excl;
    if (2 * t + 1 < nrows_b) rowptr[rowbase + 2 * t + 1] = bstart + excl + a0;
    __syncthreads();
    for (int e = bstart + t; e < bend; e += 256) {
        const long long ll = __builtin_nontemporal_load(
            reinterpret_cast<const long long*>(bcv) + e);
        const int w0 = (int)(unsigned)ll;
        const int p = atomicAdd(&cnt[w0 >> 17], 1);
        epair[p] = make_int2(w0 & 0x1FFFF, (int)(ll >> 32));
    }
}

// ---------------- MFMA GEMM: C[N,128](bf16) = A[N,K] @ W[K,128] ----------------
// Block 256 thr = 4 waves; block tile 128 rows; wave tile 32 rows x 128 cols.
// W^T staged in LDS bf16 in 128-k phases (32 KB), XOR-swizzled for b128 reads.
template <int K, bool ABF16>
__global__ __launch_bounds__(256) void mfma_gemm(const void* __restrict__ Aptr,
                                                 const float* __restrict__ W,
                                                 ushort* __restrict__ C, int nrows) {
    constexpr int KH = 128;
    __shared__ __align__(16) ushort wt[128 * KH];
    const int t = threadIdx.x;
    const int lane = t & 63;
    const int wv = t >> 6;
    const int r = lane & 15;
    const int g = lane >> 4;
    const int row_base = blockIdx.x * 128 + wv * 32;
    const unsigned xorv = (unsigned)((r & 7) << 4);
    f32x4 acc[2][8] = {};

    for (int kh = 0; kh < K; kh += KH) {
        if (kh) __syncthreads();
        for (int idx = t; idx < KH * 32; idx += 256) {
            const int c4 = (idx & 31) << 2;
            const int k = idx >> 5;
            const float4 w4 = *reinterpret_cast<const float4*>(&W[(kh + k) * 128 + c4]);
            const float wf[4] = {w4.x, w4.y, w4.z, w4.w};
            #pragma unroll
            for (int j = 0; j < 4; ++j) {
                const int c = c4 + j;
                const unsigned byteoff = (unsigned)(((c * KH + k) * 2) ^ ((c & 7) << 4));
                *reinterpret_cast<ushort*>(reinterpret_cast<char*>(wt) + byteoff) = f2bf(wf[j]);
            }
        }
        __syncthreads();

        for (int s = 0; s < KH / 32; ++s) {
            const int kbg = kh + s * 32 + g * 8;
            const int kbl = s * 32 + g * 8;
            bf16x8 a[2];
            #pragma unroll
            for (int f = 0; f < 2; ++f) {
                int row = row_base + f * 16 + r;
                if (row >= nrows) row = nrows - 1;
                if (ABF16) {
                    a[f] = *reinterpret_cast<const bf16x8*>(
                        (const ushort*)Aptr + (size_t)row * K + kbg);
                } else {
                    const float* Af = (const float*)Aptr + (size_t)row * K + kbg;
                    const float4 v0 = *reinterpret_cast<const float4*>(Af);
                    const float4 v1 = *reinterpret_cast<const float4*>(Af + 4);
                    bf16x8 av;
                    av[0] = (short)f2bf(v0.x); av[1] = (short)f2bf(v0.y);
                    av[2] = (short)f2bf(v0.z); av[3] = (short)f2bf(v0.w);
                    av[4] = (short)f2bf(v1.x); av[5] = (short)f2bf(v1.y);
                    av[6] = (short)f2bf(v1.z); av[7] = (short)f2bf(v1.w);
                    a[f] = av;
                }
            }
            #pragma unroll
            for (int c = 0; c < 8; ++c) {
                const unsigned boff = ((unsigned)(((c * 16 + r) * KH + kbl) * 2)) ^ xorv;
                const bf16x8 b = *reinterpret_cast<const bf16x8*>(
                    reinterpret_cast<char*>(wt) + boff);
                acc[0][c] = __builtin_amdgcn_mfma_f32_16x16x32_bf16(a[0], b, acc[0][c], 0, 0, 0);
                acc[1][c] = __builtin_amdgcn_mfma_f32_16x16x32_bf16(a[1], b, acc[1][c], 0, 0, 0);
            }
        }
    }
    #pragma unroll
    for (int f = 0; f < 2; ++f) {
        #pragma unroll
        for (int j = 0; j < 4; ++j) {
            const int row = row_base + f * 16 + g * 4 + j;
            if (row < nrows) {
                #pragma unroll
                for (int c = 0; c < 8; ++c) {
                    C[(size_t)row * HID + c * 16 + r] = f2bf(acc[f][c][j]);
                }
            }
        }
    }
}

// ---------------- CSR SpMM (bf16 gather), one wave per row ----------------
// 8-deep parallel gather batches; tail handled as one masked batch (no serial chain).
// Edge stream read nontemporal (keeps X L2-resident); h1 store nontemporal.
template <bool FINAL>
__global__ __launch_bounds__(256) void spmm_kernel(const int* __restrict__ row_ptr,
                                                   const int2* __restrict__ epair,
                                                   const ushort* __restrict__ X,
                                                   const float* __restrict__ bias,
                                                   const float* __restrict__ wo,
                                                   const float* __restrict__ bo,
                                                   void* __restrict__ out, int nrows) {
    const int wave = threadIdx.x >> 6;
    const int lane = threadIdx.x & 63;
    const int row = blockIdx.x * 4 + wave;
    if (row >= nrows) return;
    const int e0 = row_ptr[row];
    const int e1 = row_ptr[row + 1];
    float ax = 0.f, ay = 0.f;
    int e = e0;
    for (; e + 8 <= e1; e += 8) {
        long long ev[8];
        #pragma unroll
        for (int i = 0; i < 8; ++i)
            ev[i] = __builtin_nontemporal_load(
                reinterpret_cast<const long long*>(epair) + e + i);
        unsigned xv[8];
        #pragma unroll
        for (int i = 0; i < 8; ++i)
            xv[i] = *reinterpret_cast<const unsigned*>(
                &X[(size_t)(unsigned)(ev[i] & 0x1FFFF) * HID + lane * 2]);
        #pragma unroll
        for (int i = 0; i < 8; ++i) {
            const float v = __int_as_float((int)(ev[i] >> 32));
            ax += v * bf2f((ushort)(xv[i] & 0xffffu));
            ay += v * bf2f((ushort)(xv[i] >> 16));
        }
    }
    if (e < e1) {  // masked tail batch: parallel loads, zeroed vals
        long long ev[8];
        #pragma unroll
        for (int i = 0; i < 8; ++i) {
            const int idx = (e + i < e1) ? e + i : e1 - 1;
            ev[i] = __builtin_nontemporal_load(
                reinterpret_cast<const long long*>(epair) + idx);
        }
        unsigned xv[8];
        #pragma unroll
        for (int i = 0; i < 8; ++i)
            xv[i] = *reinterpret_cast<const unsigned*>(
                &X[(size_t)(unsigned)(ev[i] & 0x1FFFF) * HID + lane * 2]);
        #pragma unroll
        for (int i = 0; i < 8; ++i) {
            const float v = (e + i < e1) ? __int_as_float((int)(ev[i] >> 32)) : 0.f;
            ax += v * bf2f((ushort)(xv[i] & 0xffffu));
            ay += v * bf2f((ushort)(xv[i] >> 16));
        }
    }
    const float hx = fmaxf(ax + bias[lane * 2], 0.f);
    const float hy = fmaxf(ay + bias[lane * 2 + 1], 0.f);
    if (!FINAL) {
        const unsigned packed = (unsigned)f2bf(hx) | ((unsigned)f2bf(hy) << 16);
        __builtin_nontemporal_store(
            packed, reinterpret_cast<unsigned*>(out) + (size_t)row * (HID / 2) + lane);
    } else {
        float p = hx * wo[lane * 2] + hy * wo[lane * 2 + 1];
        #pragma unroll
        for (int off = 32; off > 0; off >>= 1) p += __shfl_down(p, off, 64);
        if (lane == 0) reinterpret_cast<float*>(out)[row] = p + bo[0];
    }
}

extern "C" void kernel_launch(void* const* d_in, const int* in_sizes, int n_in,
                              void* d_out, int out_size, void* d_ws, size_t ws_size,
                              hipStream_t stream) {
    const float* x        = (const float*)d_in[0];
    const int*   e_rows   = (const int*)d_in[1];
    const int*   e_cols   = (const int*)d_in[2];
    const float* e_vals   = (const float*)d_in[3];
    const float* w1       = (const float*)d_in[4];
    const float* b1       = (const float*)d_in[5];
    const float* w2       = (const float*)d_in[6];
    const float* b2       = (const float*)d_in[7];
    const float* wo       = (const float*)d_in[8];
    const float* bo       = (const float*)d_in[9];
    float* z = (float*)d_out;

    const int IN_DIM = 256;
    const int N = in_sizes[0] / IN_DIM;
    const int E = in_sizes[1];
    const int NCHUNK = (E + CHUNK_E - 1) / CHUNK_E;
    const int NBUCKET = (N + 511) >> 9;
    const int NTOT = NBUCKET * NCHUNK;
    const int NSEG = (NTOT + 511) / 512;  // must be <= 1024

    size_t off = 0;
    auto alloc = [&](size_t bytes) {
        void* p = (char*)d_ws + off;
        off += (bytes + 255) & ~(size_t)255;
        return p;
    };
    ushort* bufA  = (ushort*)alloc((size_t)N * HID * 2);   // xw, later h1w (bf16)
    ushort* bufB  = (ushort*)alloc((size_t)N * HID * 2);   // h1 (bf16)
    int*   rowptr = (int*)alloc((size_t)(N + 1) * 4);
    int*   histT  = (int*)alloc((size_t)NTOT * 4);
    int*   bsums  = (int*)alloc((size_t)NSEG * 4);
    int2*  epair  = (int2*)alloc((size_t)E * 8);
    int2*  bcv    = (int2*)alloc((size_t)E * 8);
    (void)ws_size;

    // ---- CSR build ----
    bhist_kernel<<<NCHUNK, 256, 0, stream>>>(e_rows, histT, E, NBUCKET, NCHUNK);
    bsum_kernel<<<NSEG, 256, 0, stream>>>(histT, bsums, NTOT);
    bscan_kernel<<<1, 1024, 0, stream>>>(bsums, NSEG, rowptr, N, E);
    bemit_kernel<<<NSEG, 256, 0, stream>>>(histT, bsums, NTOT);
    partition_kernel<<<NCHUNK, 256, 0, stream>>>(e_rows, e_cols, e_vals, histT, bcv, E, NBUCKET, NCHUNK);
    finalize_kernel<<<NBUCKET, 256, 0, stream>>>(bcv, histT, rowptr, epair, N, E, NCHUNK, NBUCKET);

    const int gemm_grid = (N + 127) / 128;
    // ---- layer 1 ----
    mfma_gemm<256, false><<<gemm_grid, 256, 0, stream>>>(x, w1, bufA, N);
    spmm_kernel<false><<<(N + 3) / 4, 256, 0, stream>>>(rowptr, epair, bufA, b1, nullptr, nullptr, bufB, N);

    // ---- layer 2 + output ----
    mfma_gemm<128, true><<<gemm_grid, 256, 0, stream>>>(bufB, w2, bufA, N);
    spmm_kernel<true><<<(N + 3) / 4, 256, 0, stream>>>(rowptr, epair, bufA, b2, wo, bo, z, N);
}